// Round 2
// baseline (576.387 us; speedup 1.0000x reference)
//
#include <hip/hip_runtime.h>
#include <math.h>

#define N_  32
#define C_  64
#define HW  192          // h == w == 192
#define NC  (N_ * C_)    // 2048 (n,c) tiles

__device__ __forceinline__ float wave_max(float v) {
#pragma unroll
    for (int off = 32; off; off >>= 1) v = fmaxf(v, __shfl_xor(v, off));
    return v;
}
__device__ __forceinline__ float wave_sum(float v) {
#pragma unroll
    for (int off = 32; off; off >>= 1) v += __shfl_xor(v, off);
    return v;
}

// 256-thread block reductions (4 waves), red[] is shared float[4]
__device__ __forceinline__ float block_max(float v, float* red) {
    const int w = threadIdx.x >> 6, lane = threadIdx.x & 63;
    v = wave_max(v);
    if (lane == 0) red[w] = v;
    __syncthreads();
    float r = fmaxf(fmaxf(red[0], red[1]), fmaxf(red[2], red[3]));
    __syncthreads();
    return r;
}
__device__ __forceinline__ float block_sum(float v, float* red) {
    const int w = threadIdx.x >> 6, lane = threadIdx.x & 63;
    v = wave_sum(v);
    if (lane == 0) red[w] = v;
    __syncthreads();
    float r = (red[0] + red[1]) + (red[2] + red[3]);
    __syncthreads();
    return r;
}

#define FMAX4(a, v)                                                    \
    do {                                                               \
        (a).x = fmaxf((a).x, (v).x); (a).y = fmaxf((a).y, (v).y);      \
        (a).z = fmaxf((a).z, (v).z); (a).w = fmaxf((a).w, (v).w);      \
    } while (0)

// One block per (n,c) tile. Streams both 192x192 f32 tiles with 12
// independent float4 loads in flight per thread per pass (MLP-deep).
// Produces simpos[b] and the 4 normalized vectors A -> Aout[b][4][192].
__global__ __launch_bounds__(256) void k_stage1(const float* __restrict__ outp,
                                                const float* __restrict__ tgtp,
                                                float* __restrict__ simpos,
                                                float* __restrict__ Aout) {
    __shared__ float4 cpart[32][49];   // padded: breaks 8-way ds_write conflict
    __shared__ float rowm[2][HW];
    __shared__ float colm[2][HW];
    __shared__ float A[4][HW];         // 0:Ao_h 1:Ao_w 2:At_h 3:At_w
    __shared__ float red[4];

    const int b   = blockIdx.x;
    const int tid = threadIdx.x;
    const int j   = tid & 7;           // col-group within row (8 per row)
    const int r   = tid >> 3;          // 0..31: row within pass
    const float NEG = -INFINITY;

    const float* X0 = outp + (size_t)b * (HW * HW);
    const float* X1 = tgtp + (size_t)b * (HW * HW);

    float4 cm0[6], cm1[6];
#pragma unroll
    for (int k = 0; k < 6; ++k) {
        cm0[k] = make_float4(NEG, NEG, NEG, NEG);
        cm1[k] = cm0[k];
    }

    for (int p = 0; p < 6; ++p) {
        const int row = p * 32 + r;
        const float4* r0 = (const float4*)(X0 + row * HW);
        const float4* r1 = (const float4*)(X1 + row * HW);
        float4 v0[6], v1[6];
#pragma unroll
        for (int k = 0; k < 6; ++k) v0[k] = r0[j + 8 * k];
#pragma unroll
        for (int k = 0; k < 6; ++k) v1[k] = r1[j + 8 * k];

        float rm0 = NEG, rm1 = NEG;
#pragma unroll
        for (int k = 0; k < 6; ++k) {
            FMAX4(cm0[k], v0[k]);
            FMAX4(cm1[k], v1[k]);
            rm0 = fmaxf(rm0, fmaxf(fmaxf(v0[k].x, v0[k].y), fmaxf(v0[k].z, v0[k].w)));
            rm1 = fmaxf(rm1, fmaxf(fmaxf(v1[k].x, v1[k].y), fmaxf(v1[k].z, v1[k].w)));
        }
        // reduce over the 8 col-group lanes (consecutive lanes, 8 | 64)
#pragma unroll
        for (int off = 1; off < 8; off <<= 1) {
            rm0 = fmaxf(rm0, __shfl_xor(rm0, off));
            rm1 = fmaxf(rm1, __shfl_xor(rm1, off));
        }
        if (j == 0) { rowm[0][row] = rm0; rowm[1][row] = rm1; }
    }

    // column-max finalize, one tensor at a time through the shared tile
    for (int t = 0; t < 2; ++t) {
        __syncthreads();
#pragma unroll
        for (int k = 0; k < 6; ++k) cpart[r][j + 8 * k] = t ? cm1[k] : cm0[k];
        __syncthreads();
        if (tid < HW) {
            const int c4 = tid >> 2, comp = tid & 3;
            float m = NEG;
#pragma unroll 4
            for (int rr = 0; rr < 32; ++rr) {
                m = fmaxf(m, ((const float*)&cpart[rr][c4])[comp]);
            }
            colm[t][tid] = m;
        }
    }
    __syncthreads();

    // softmax + l2norm fused: a_i = exp(x_i - M) / ||exp(x - M)||
    // (softmax denominator cancels in cosine normalization; eps clamp inert)
    for (int v = 0; v < 4; ++v) {
        const float* src = (v == 0) ? rowm[0] : (v == 1) ? colm[0]
                         : (v == 2) ? rowm[1] : colm[1];
        float x = (tid < HW) ? src[tid] : NEG;
        float M = block_max(x, red);
        float e = (tid < HW) ? expf(x - M) : 0.0f;
        float ss = block_sum(e * e, red);
        if (tid < HW) A[v][tid] = e / sqrtf(ss);
    }
    __syncthreads();

    // sim_pos[b] = 0.5*(dot(Ao_h,At_h) + dot(Ao_w,At_w))
    float pd = (tid < HW) ? (A[0][tid] * A[2][tid] + A[1][tid] * A[3][tid]) : 0.0f;
    float sp = block_sum(pd, red);
    if (tid == 0) simpos[b] = 0.5f * sp;

    // store the 4 vectors (768 floats), coalesced
    float* dst = Aout + (size_t)b * 4 * HW;
    const float* Af = (const float*)A;
    for (int i = tid; i < 4 * HW; i += 256) dst[i] = Af[i];
}

// One block per n: channel-sum the A vectors, sim, loss.
__global__ __launch_bounds__(256) void k_stage2(const float* __restrict__ simpos,
                                                const float* __restrict__ Aout,
                                                float* __restrict__ loss) {
    __shared__ float S[4 * HW];
    __shared__ float red[4];
    const int n = blockIdx.x, tid = threadIdx.x;
    const float* base = Aout + (size_t)n * C_ * 4 * HW;

    float a0 = 0.0f, a1 = 0.0f, a2 = 0.0f;
    for (int c = 0; c < C_; ++c) {
        const float* a = base + c * 4 * HW;
        a0 += a[tid];
        a1 += a[tid + 256];
        a2 += a[tid + 512];
    }
    S[tid] = a0; S[tid + 256] = a1; S[tid + 512] = a2;
    __syncthreads();

    // vec order per block: 0=Ao_h 1=Ao_w 2=At_h 3=At_w
    float p = 0.0f;
    if (tid < HW)
        p = S[0 * HW + tid] * S[2 * HW + tid] + S[1 * HW + tid] * S[3 * HW + tid];
    float sim = 0.5f * block_sum(p, red);

    if (tid < C_) {
        loss[n * C_ + tid] =
            -logf(simpos[n * C_ + tid] / sim) * (1.0f / (N_ * C_));
    }
}

extern "C" void kernel_launch(void* const* d_in, const int* in_sizes, int n_in,
                              void* d_out, int out_size, void* d_ws, size_t ws_size,
                              hipStream_t stream) {
    const float* outp = (const float*)d_in[0];
    const float* tgtp = (const float*)d_in[1];
    float* simpos = (float*)d_ws;              // NC floats
    float* Aout   = simpos + NC;               // NC*4*HW floats (~6.3 MB)
    float* lossp  = (float*)d_out;             // NC floats

    hipLaunchKernelGGL(k_stage1, dim3(NC), dim3(256), 0, stream,
                       outp, tgtp, simpos, Aout);
    hipLaunchKernelGGL(k_stage2, dim3(N_), dim3(256), 0, stream,
                       simpos, Aout, lossp);
}